// Round 1
// baseline (334.168 us; speedup 1.0000x reference)
//
#include <hip/hip_runtime.h>
#include <stdint.h>
#include <math.h>

typedef unsigned int u32;
typedef __bf16 bf16x8 __attribute__((ext_vector_type(8)));
typedef float  f32x4  __attribute__((ext_vector_type(4)));
typedef unsigned short u16x4 __attribute__((ext_vector_type(4)));

#define DEV __device__ __forceinline__

DEV unsigned short f2b(float f) {
  u32 x = __builtin_bit_cast(u32, f);
  u32 r = (x + 0x7fffu + ((x >> 16) & 1u)) >> 16;
  return (unsigned short)r;
}
DEV float b2f(unsigned short u) { return __builtin_bit_cast(float, ((u32)u) << 16); }

// async global->LDS, 16B per lane. LDS dest = wave-uniform base + lane*16.
DEV void gl2lds16(const void* g, void* l) {
  __builtin_amdgcn_global_load_lds((const __attribute__((address_space(1))) u32*)g,
                                   (__attribute__((address_space(3))) u32*)l, 16, 0, 0);
}

// ---------------- small prep kernels ----------------

__global__ void rope_tables_k(float* __restrict__ ct, float* __restrict__ st) {
  int s = blockIdx.x;          // 0..2047
  int d = threadIdx.x;         // 0..63
  double inv = pow(10000.0, -(double)d / 64.0);
  double a = (double)s * inv;
  ct[s * 64 + d] = (float)cos(a);
  st[s * 64 + d] = (float)sin(a);
}

__global__ void cvt4_k(const float* __restrict__ in, unsigned short* __restrict__ out, int n4) {
  int i = blockIdx.x * blockDim.x + threadIdx.x;
  if (i >= n4) return;
  float4 v = ((const float4*)in)[i];
  u16x4 r = { f2b(v.x), f2b(v.y), f2b(v.z), f2b(v.w) };
  *(u16x4*)(out + (size_t)i * 4) = r;
}

// W [K][N] f32 -> Wt [N][K] bf16
__global__ void tcvt_k(const float* __restrict__ in, unsigned short* __restrict__ out,
                       int Kdim, int Ndim) {
  __shared__ float t[32][33];
  int n0 = blockIdx.x * 32, k0 = blockIdx.y * 32;
  int tx = threadIdx.x, ty = threadIdx.y;  // 32 x 8
  for (int i = ty; i < 32; i += 8) t[i][tx] = in[(size_t)(k0 + i) * Ndim + n0 + tx];
  __syncthreads();
  for (int i = ty; i < 32; i += 8)
    out[(size_t)(n0 + i) * Kdim + k0 + tx] = f2b(t[tx][i]);
}

template <bool SC>
__global__ void rope_k(unsigned short* __restrict__ p, const float* __restrict__ ct,
                       const float* __restrict__ st, int total) {
  int i = blockIdx.x * blockDim.x + threadIdx.x;
  if (i >= total) return;
  int d = i & 63;
  int s = (i >> 6) & 2047;
  size_t base = ((size_t)(i >> 17) * 2048 + s) * 128;
  float x1 = b2f(p[base + d]), x2 = b2f(p[base + d + 64]);
  float c = ct[s * 64 + d], sn = st[s * 64 + d];
  float o1 = x1 * c - x2 * sn;
  float o2 = x2 * c + x1 * sn;
  if (SC) { o1 *= 0.08838834764831845f; o2 *= 0.08838834764831845f; }  // 1/sqrt(128)
  p[base + d] = f2b(o1);
  p[base + d + 64] = f2b(o2);
}

// ---------------- GEMM: C = A * Bt^T (+bias), m97 structure ----------------
// A [M][K] bf16 row-major, Bt [N][K] bf16 row-major. 128x128 tile, BK=64,
// 4 waves (2x2), double-buffered LDS, global_load_lds staging with XOR swizzle
// applied to the per-lane GLOBAL source (LDS stays linear), swizzled ds_read.
// MODE 0: fp32 out[row*N+col]        (no bias)
// MODE 1: bf16 + bias -> [B][h][2048][128]   (nheads given)
// MODE 2: bf16 + bias -> [B][h][128][2048]   (V transposed)
template <int MODE>
__global__ __launch_bounds__(256) void gemm_bt_k(
    const unsigned short* __restrict__ A, const unsigned short* __restrict__ Bt,
    float* __restrict__ outF, unsigned short* __restrict__ outB,
    const float* __restrict__ bias, int Mdim, int Ndim, int Kdim, int nheads) {
  __shared__ alignas(16) unsigned short As[2][128 * 64];
  __shared__ alignas(16) unsigned short Bs[2][128 * 64];

  const int tid = threadIdx.x, lane = tid & 63, wid = tid >> 6;
  const int wm = wid >> 1, wn = wid & 1;
  const int m0 = blockIdx.y << 7, n0 = blockIdx.x << 7;
  const int NT = Kdim >> 6;
  const int lrow = lane >> 3, lslot = lane & 7;
  const int cl = lane & 15, g = lane >> 4;

  f32x4 acc[4][4];
#pragma unroll
  for (int i = 0; i < 4; ++i)
#pragma unroll
    for (int j = 0; j < 4; ++j) acc[i][j] = (f32x4){0.f, 0.f, 0.f, 0.f};

  auto stage = [&](int t, int buf) {
    const int k0 = t << 6;
#pragma unroll
    for (int i = 0; i < 4; ++i) {
      int chunk = wid + (i << 2);            // 0..15, 1KB each (8 rows x 128B)
      int row = (chunk << 3) + lrow;
      int sl = lslot ^ (row & 7);
      gl2lds16(A + ((size_t)(m0 + row) * Kdim + k0 + (sl << 3)),
               &As[buf][(chunk << 9) + (lane << 3)]);
    }
#pragma unroll
    for (int i = 0; i < 4; ++i) {
      int chunk = wid + (i << 2);
      int row = (chunk << 3) + lrow;
      int sl = lslot ^ (row & 7);
      gl2lds16(Bt + ((size_t)(n0 + row) * Kdim + k0 + (sl << 3)),
               &Bs[buf][(chunk << 9) + (lane << 3)]);
    }
  };

  stage(0, 0);
  __syncthreads();

  for (int t = 0; t < NT; ++t) {
    int buf = t & 1;
    if (t + 1 < NT) stage(t + 1, buf ^ 1);
    bf16x8 af[4][2], bfr[4][2];
#pragma unroll
    for (int mt = 0; mt < 4; ++mt) {
      int row = (wm << 6) + (mt << 4) + cl;
#pragma unroll
      for (int kc = 0; kc < 2; ++kc) {
        int sl = ((kc << 2) + g) ^ (row & 7);
        af[mt][kc] = *(const bf16x8*)&As[buf][(row << 6) + (sl << 3)];
      }
    }
#pragma unroll
    for (int nt = 0; nt < 4; ++nt) {
      int row = (wn << 6) + (nt << 4) + cl;
#pragma unroll
      for (int kc = 0; kc < 2; ++kc) {
        int sl = ((kc << 2) + g) ^ (row & 7);
        bfr[nt][kc] = *(const bf16x8*)&Bs[buf][(row << 6) + (sl << 3)];
      }
    }
#pragma unroll
    for (int kc = 0; kc < 2; ++kc)
#pragma unroll
      for (int mt = 0; mt < 4; ++mt)
#pragma unroll
        for (int nt = 0; nt < 4; ++nt)
          acc[mt][nt] = __builtin_amdgcn_mfma_f32_16x16x32_bf16(
              af[mt][kc], bfr[nt][kc], acc[mt][nt], 0, 0, 0);
    __syncthreads();
  }

  const int rb = g << 2;
#pragma unroll
  for (int mt = 0; mt < 4; ++mt) {
#pragma unroll
    for (int nt = 0; nt < 4; ++nt) {
      int col = n0 + (wn << 6) + (nt << 4) + cl;
#pragma unroll
      for (int r = 0; r < 4; ++r) {
        int row = m0 + (wm << 6) + (mt << 4) + rb + r;
        float v = acc[mt][nt][r];
        if constexpr (MODE == 0) {
          outF[(size_t)row * Ndim + col] = v;
        } else {
          v += bias[col];
          int bb = row >> 11, s = row & 2047, h = col >> 7, d = col & 127;
          if constexpr (MODE == 1)
            outB[((((size_t)bb * nheads + h) << 11) + s) * 128 + d] = f2b(v);
          else
            outB[((((size_t)bb * nheads + h) << 7) + d) * 2048 + s] = f2b(v);
        }
      }
    }
  }
}

// ---------------- flash attention ----------------
// Qb [B][16][S][128] (pre-scaled by 1/sqrt(D), RoPE'd) bf16
// Kb [B][4][S][128] (RoPE'd) bf16, Vt [B][4][128][S] bf16
// AO [B*S][2048] bf16.  512 threads = 8 waves x 16 q-rows, KVBLK=64.
__global__ __launch_bounds__(512) void attn_k(
    const unsigned short* __restrict__ Qb, const unsigned short* __restrict__ Kb,
    const unsigned short* __restrict__ Vt, unsigned short* __restrict__ AO) {
  __shared__ alignas(16) unsigned short Ks[2][64 * 128];   // [kv][d]
  __shared__ alignas(16) unsigned short Vs[2][128 * 64];   // [d][kv]
  __shared__ alignas(16) unsigned short Ps[8][16 * 64];    // per-wave [q][kv]

  const int tid = threadIdx.x, lane = tid & 63, wid = tid >> 6;
  const int bh = blockIdx.y;
  const int b = bh >> 4, h = bh & 15, kvh = h >> 2;
  const int q0 = blockIdx.x << 7;
  const int cl = lane & 15, g = lane >> 4;

  const unsigned short* Qp = Qb + ((size_t)(b * 16 + h) << 11) * 128;
  const unsigned short* Kp = Kb + ((size_t)(b * 4 + kvh) << 11) * 128;
  const unsigned short* Vp = Vt + ((size_t)(b * 4 + kvh) << 7) * 2048;

  bf16x8 qf[4];
  {
    int qrow = q0 + (wid << 4) + cl;
#pragma unroll
    for (int kc = 0; kc < 4; ++kc)
      qf[kc] = *(const bf16x8*)(Qp + (size_t)qrow * 128 + (kc << 5) + (g << 3));
  }

  f32x4 o[8];
#pragma unroll
  for (int i = 0; i < 8; ++i) o[i] = (f32x4){0.f, 0.f, 0.f, 0.f};
  float mrow[4] = {-3e38f, -3e38f, -3e38f, -3e38f};
  float lrow[4] = {0.f, 0.f, 0.f, 0.f};

  const int lrow8 = lane >> 3, lslot8 = lane & 7;
  const int lrow4 = lane >> 4, lslot16 = lane & 15;

  auto stage = [&](int t, int buf) {
    int kv0 = t << 6;
#pragma unroll
    for (int i = 0; i < 2; ++i) {           // K: 16 chunks (4 rows x 256B each)
      int chunk = wid + (i << 3);
      int row = (chunk << 2) + lrow4;
      int sl = lslot16 ^ (row & 7);
      gl2lds16(Kp + ((size_t)(kv0 + row) << 7) + (sl << 3),
               &Ks[buf][(chunk << 9) + (lane << 3)]);
    }
#pragma unroll
    for (int i = 0; i < 2; ++i) {           // Vt: 16 chunks (8 rows x 128B each)
      int chunk = wid + (i << 3);
      int row = (chunk << 3) + lrow8;
      int sl = lslot8 ^ (row & 7);
      gl2lds16(Vp + ((size_t)row << 11) + kv0 + (sl << 3),
               &Vs[buf][(chunk << 9) + (lane << 3)]);
    }
  };

  stage(0, 0);
  __syncthreads();

  for (int t = 0; t < 32; ++t) {
    int buf = t & 1;
    if (t + 1 < 32) stage(t + 1, buf ^ 1);

    // S = Q K^T   (scale pre-baked into Q)
    f32x4 sf[4];
#pragma unroll
    for (int nt = 0; nt < 4; ++nt) sf[nt] = (f32x4){0.f, 0.f, 0.f, 0.f};
#pragma unroll
    for (int kc = 0; kc < 4; ++kc) {
#pragma unroll
      for (int nt = 0; nt < 4; ++nt) {
        int row = (nt << 4) + cl;                    // kv row
        int sl = ((kc << 2) + g) ^ (row & 7);        // 16 slots per 256B row
        bf16x8 kf = *(const bf16x8*)&Ks[buf][(row << 7) + (sl << 3)];
        sf[nt] = __builtin_amdgcn_mfma_f32_16x16x32_bf16(qf[kc], kf, sf[nt], 0, 0, 0);
      }
    }

    // online softmax: rows r=(g*4+j), cols spread over 16 lanes
    float mx[4];
#pragma unroll
    for (int j = 0; j < 4; ++j)
      mx[j] = fmaxf(fmaxf(sf[0][j], sf[1][j]), fmaxf(sf[2][j], sf[3][j]));
#pragma unroll
    for (int msk = 1; msk < 16; msk <<= 1)
#pragma unroll
      for (int j = 0; j < 4; ++j) mx[j] = fmaxf(mx[j], __shfl_xor(mx[j], msk));

    float alpha[4], rs[4];
#pragma unroll
    for (int j = 0; j < 4; ++j) {
      float mn = fmaxf(mrow[j], mx[j]);
      alpha[j] = __expf(mrow[j] - mn);
      mrow[j] = mn;
      rs[j] = 0.f;
    }
#pragma unroll
    for (int nt = 0; nt < 4; ++nt) {
#pragma unroll
      for (int j = 0; j < 4; ++j) {
        float p = __expf(sf[nt][j] - mrow[j]);
        rs[j] += p;
        int r = (g << 2) + j;
        int col = (nt << 4) + cl;
        int sl = (col >> 3) ^ (r & 7);
        Ps[wid][(r << 6) + (sl << 3) + (col & 7)] = f2b(p);
      }
    }
#pragma unroll
    for (int msk = 1; msk < 16; msk <<= 1)
#pragma unroll
      for (int j = 0; j < 4; ++j) rs[j] += __shfl_xor(rs[j], msk);
#pragma unroll
    for (int j = 0; j < 4; ++j) lrow[j] = lrow[j] * alpha[j] + rs[j];
#pragma unroll
    for (int dt = 0; dt < 8; ++dt)
#pragma unroll
      for (int j = 0; j < 4; ++j) o[dt][j] *= alpha[j];

    // O += P V
    bf16x8 pa[2];
#pragma unroll
    for (int kc = 0; kc < 2; ++kc) {
      int row = cl;                                  // q row
      int sl = ((kc << 2) + g) ^ (row & 7);
      pa[kc] = *(const bf16x8*)&Ps[wid][(row << 6) + (sl << 3)];
    }
#pragma unroll
    for (int dt = 0; dt < 8; ++dt) {
#pragma unroll
      for (int kc = 0; kc < 2; ++kc) {
        int row = (dt << 4) + cl;                    // d row of Vt
        int sl = ((kc << 2) + g) ^ (row & 7);
        bf16x8 vb = *(const bf16x8*)&Vs[buf][(row << 6) + (sl << 3)];
        o[dt] = __builtin_amdgcn_mfma_f32_16x16x32_bf16(pa[kc], vb, o[dt], 0, 0, 0);
      }
    }
    __syncthreads();
  }

  size_t row_base = (size_t)b * 2048 + q0 + (wid << 4) + (g << 2);
  size_t col_base = (size_t)h * 128;
#pragma unroll
  for (int dt = 0; dt < 8; ++dt) {
#pragma unroll
    for (int j = 0; j < 4; ++j) {
      float v = o[dt][j] / lrow[j];
      AO[(row_base + j) * 2048 + col_base + (dt << 4) + cl] = f2b(v);
    }
  }
}

// ---------------- launch ----------------
extern "C" void kernel_launch(void* const* d_in, const int* in_sizes, int n_in,
                              void* d_out, int out_size, void* d_ws, size_t ws_size,
                              hipStream_t stream) {
  const float* X  = (const float*)d_in[0];
  const float* Wq = (const float*)d_in[1];
  const float* bq = (const float*)d_in[2];
  const float* Wk = (const float*)d_in[3];
  const float* bk = (const float*)d_in[4];
  const float* Wv = (const float*)d_in[5];
  const float* bv = (const float*)d_in[6];
  const float* Wo = (const float*)d_in[7];
  float* out = (float*)d_out;

  char* ws = (char*)d_ws;
  size_t off = 0;
  auto alloc = [&](size_t bytes) {
    char* p = ws + off;
    off += (bytes + 255) & ~(size_t)255;
    return p;
  };
  unsigned short* Xb  = (unsigned short*)alloc(4096ull * 2048 * 2);
  unsigned short* Wqt = (unsigned short*)alloc(2048ull * 2048 * 2);
  unsigned short* Wkt = (unsigned short*)alloc(512ull * 2048 * 2);
  unsigned short* Wvt = (unsigned short*)alloc(512ull * 2048 * 2);
  unsigned short* Wot = (unsigned short*)alloc(2048ull * 2048 * 2);
  unsigned short* Qb  = (unsigned short*)alloc(2ull * 16 * 2048 * 128 * 2);
  unsigned short* Kb  = (unsigned short*)alloc(2ull * 4 * 2048 * 128 * 2);
  unsigned short* Vt  = (unsigned short*)alloc(2ull * 4 * 128 * 2048 * 2);
  unsigned short* AO  = (unsigned short*)alloc(4096ull * 2048 * 2);
  float* ctab = (float*)alloc(2048ull * 64 * 4);
  float* stab = (float*)alloc(2048ull * 64 * 4);

  rope_tables_k<<<dim3(2048), dim3(64), 0, stream>>>(ctab, stab);
  cvt4_k<<<dim3(8192), dim3(256), 0, stream>>>(X, Xb, 2097152);
  tcvt_k<<<dim3(64, 64), dim3(32, 8), 0, stream>>>(Wq, Wqt, 2048, 2048);
  tcvt_k<<<dim3(16, 64), dim3(32, 8), 0, stream>>>(Wk, Wkt, 2048, 512);
  tcvt_k<<<dim3(16, 64), dim3(32, 8), 0, stream>>>(Wv, Wvt, 2048, 512);
  tcvt_k<<<dim3(64, 64), dim3(32, 8), 0, stream>>>(Wo, Wot, 2048, 2048);

  gemm_bt_k<1><<<dim3(16, 32), dim3(256), 0, stream>>>(Xb, Wqt, nullptr, Qb, bq, 4096, 2048, 2048, 16);
  gemm_bt_k<1><<<dim3(4, 32),  dim3(256), 0, stream>>>(Xb, Wkt, nullptr, Kb, bk, 4096, 512, 2048, 4);
  gemm_bt_k<2><<<dim3(4, 32),  dim3(256), 0, stream>>>(Xb, Wvt, nullptr, Vt, bv, 4096, 512, 2048, 4);

  rope_k<true><<<dim3(16384), dim3(256), 0, stream>>>(Qb, ctab, stab, 4194304);
  rope_k<false><<<dim3(4096), dim3(256), 0, stream>>>(Kb, ctab, stab, 1048576);

  attn_k<<<dim3(16, 32), dim3(512), 0, stream>>>(Qb, Kb, Vt, AO);

  gemm_bt_k<0><<<dim3(16, 32), dim3(256), 0, stream>>>(AO, Wot, out, nullptr, nullptr, 4096, 2048, 2048, 0);
}

// Round 2
// 266.979 us; speedup vs baseline: 1.2517x; 1.2517x over previous
//
#include <hip/hip_runtime.h>
#include <stdint.h>
#include <math.h>

typedef unsigned int u32;
typedef __bf16 bf16x8 __attribute__((ext_vector_type(8)));
typedef float  f32x4  __attribute__((ext_vector_type(4)));
typedef float  f32x16 __attribute__((ext_vector_type(16)));
typedef unsigned int u32x4 __attribute__((ext_vector_type(4)));
typedef unsigned short u16x4 __attribute__((ext_vector_type(4)));

#define DEV __device__ __forceinline__

DEV unsigned short f2b(float f) {
  u32 x = __builtin_bit_cast(u32, f);
  u32 r = (x + 0x7fffu + ((x >> 16) & 1u)) >> 16;
  return (unsigned short)r;
}
DEV float b2f(unsigned short u) { return __builtin_bit_cast(float, ((u32)u) << 16); }

DEV u32 cvtpk_bf16(float lo, float hi) {
  u32 r;
  asm("v_cvt_pk_bf16_f32 %0, %1, %2" : "=v"(r) : "v"(lo), "v"(hi));
  return r;
}
DEV void pl32swap(u32& a, u32& b) {
  asm("v_permlane32_swap_b32 %0, %1" : "+v"(a), "+v"(b));
}

// async global->LDS, 16B per lane. LDS dest = wave-uniform base + lane*16.
DEV void gl2lds16(const void* g, void* l) {
  __builtin_amdgcn_global_load_lds((const __attribute__((address_space(1))) u32*)g,
                                   (__attribute__((address_space(3))) u32*)l, 16, 0, 0);
}

// ---------------- small prep kernels ----------------

__global__ void rope_tables_k(float* __restrict__ ct, float* __restrict__ st) {
  int s = blockIdx.x;          // 0..2047
  int d = threadIdx.x;         // 0..63
  double inv = pow(10000.0, -(double)d / 64.0);
  double a = (double)s * inv;
  ct[s * 64 + d] = (float)cos(a);
  st[s * 64 + d] = (float)sin(a);
}

__global__ void cvt4_k(const float* __restrict__ in, unsigned short* __restrict__ out, int n4) {
  int i = blockIdx.x * blockDim.x + threadIdx.x;
  if (i >= n4) return;
  float4 v = ((const float4*)in)[i];
  u16x4 r = { f2b(v.x), f2b(v.y), f2b(v.z), f2b(v.w) };
  *(u16x4*)(out + (size_t)i * 4) = r;
}

// W [K][N] f32 -> Wt [N][K] bf16
__global__ void tcvt_k(const float* __restrict__ in, unsigned short* __restrict__ out,
                       int Kdim, int Ndim) {
  __shared__ float t[32][33];
  int n0 = blockIdx.x * 32, k0 = blockIdx.y * 32;
  int tx = threadIdx.x, ty = threadIdx.y;  // 32 x 8
  for (int i = ty; i < 32; i += 8) t[i][tx] = in[(size_t)(k0 + i) * Ndim + n0 + tx];
  __syncthreads();
  for (int i = ty; i < 32; i += 8)
    out[(size_t)(n0 + i) * Kdim + k0 + tx] = f2b(t[tx][i]);
}

template <bool SC>
__global__ void rope_k(unsigned short* __restrict__ p, const float* __restrict__ ct,
                       const float* __restrict__ st, int total) {
  int i = blockIdx.x * blockDim.x + threadIdx.x;
  if (i >= total) return;
  int d = i & 63;
  int s = (i >> 6) & 2047;
  size_t base = ((size_t)(i >> 17) * 2048 + s) * 128;
  float x1 = b2f(p[base + d]), x2 = b2f(p[base + d + 64]);
  float c = ct[s * 64 + d], sn = st[s * 64 + d];
  float o1 = x1 * c - x2 * sn;
  float o2 = x2 * c + x1 * sn;
  if (SC) { o1 *= 0.08838834764831845f; o2 *= 0.08838834764831845f; }  // 1/sqrt(128)
  p[base + d] = f2b(o1);
  p[base + d + 64] = f2b(o2);
}

// ---------------- GEMM: C = A * Bt^T (+bias), m97 structure ----------------
// MODE 0: fp32 out[row*Ndim+col]   (no bias)  -- O projection
// MODE 3: fused QKV epilogue: cols [0,2048) -> Qb [B][16][S][128] (+bq)
//         cols [2048,2560) -> Kb [B][4][S][128] (+bk)
//         cols [2560,3072) -> Vt [B][4][128][S] (+bv, transposed)
template <int MODE>
__global__ __launch_bounds__(256) void gemm_bt_k(
    const unsigned short* __restrict__ A, const unsigned short* __restrict__ Bt,
    float* __restrict__ outF,
    unsigned short* __restrict__ outQ, unsigned short* __restrict__ outK,
    unsigned short* __restrict__ outV,
    const float* __restrict__ bq_, const float* __restrict__ bk_,
    const float* __restrict__ bv_, int Mdim, int Ndim, int Kdim) {
  __shared__ alignas(16) unsigned short As[2][128 * 64];
  __shared__ alignas(16) unsigned short Bs[2][128 * 64];

  const int tid = threadIdx.x, lane = tid & 63, wid = tid >> 6;
  const int wm = wid >> 1, wn = wid & 1;
  const int m0 = blockIdx.y << 7, n0 = blockIdx.x << 7;
  const int NT = Kdim >> 6;
  const int lrow = lane >> 3, lslot = lane & 7;
  const int cl = lane & 15, g = lane >> 4;

  f32x4 acc[4][4];
#pragma unroll
  for (int i = 0; i < 4; ++i)
#pragma unroll
    for (int j = 0; j < 4; ++j) acc[i][j] = (f32x4){0.f, 0.f, 0.f, 0.f};

  auto stage = [&](int t, int buf) {
    const int k0 = t << 6;
#pragma unroll
    for (int i = 0; i < 4; ++i) {
      int chunk = wid + (i << 2);            // 0..15, 1KB each (8 rows x 128B)
      int row = (chunk << 3) + lrow;
      int sl = lslot ^ (row & 7);
      gl2lds16(A + ((size_t)(m0 + row) * Kdim + k0 + (sl << 3)),
               &As[buf][(chunk << 9) + (lane << 3)]);
    }
#pragma unroll
    for (int i = 0; i < 4; ++i) {
      int chunk = wid + (i << 2);
      int row = (chunk << 3) + lrow;
      int sl = lslot ^ (row & 7);
      gl2lds16(Bt + ((size_t)(n0 + row) * Kdim + k0 + (sl << 3)),
               &Bs[buf][(chunk << 9) + (lane << 3)]);
    }
  };

  stage(0, 0);
  __syncthreads();

  for (int t = 0; t < NT; ++t) {
    int buf = t & 1;
    if (t + 1 < NT) stage(t + 1, buf ^ 1);
    bf16x8 af[4][2], bfr[4][2];
#pragma unroll
    for (int mt = 0; mt < 4; ++mt) {
      int row = (wm << 6) + (mt << 4) + cl;
#pragma unroll
      for (int kc = 0; kc < 2; ++kc) {
        int sl = ((kc << 2) + g) ^ (row & 7);
        af[mt][kc] = *(const bf16x8*)&As[buf][(row << 6) + (sl << 3)];
      }
    }
#pragma unroll
    for (int nt = 0; nt < 4; ++nt) {
      int row = (wn << 6) + (nt << 4) + cl;
#pragma unroll
      for (int kc = 0; kc < 2; ++kc) {
        int sl = ((kc << 2) + g) ^ (row & 7);
        bfr[nt][kc] = *(const bf16x8*)&Bs[buf][(row << 6) + (sl << 3)];
      }
    }
#pragma unroll
    for (int kc = 0; kc < 2; ++kc)
#pragma unroll
      for (int mt = 0; mt < 4; ++mt)
#pragma unroll
        for (int nt = 0; nt < 4; ++nt)
          acc[mt][nt] = __builtin_amdgcn_mfma_f32_16x16x32_bf16(
              af[mt][kc], bfr[nt][kc], acc[mt][nt], 0, 0, 0);
    __syncthreads();
  }

  const int rb = g << 2;
#pragma unroll
  for (int mt = 0; mt < 4; ++mt) {
#pragma unroll
    for (int nt = 0; nt < 4; ++nt) {
      int col = n0 + (wn << 6) + (nt << 4) + cl;
#pragma unroll
      for (int r = 0; r < 4; ++r) {
        int row = m0 + (wm << 6) + (mt << 4) + rb + r;
        float v = acc[mt][nt][r];
        if constexpr (MODE == 0) {
          outF[(size_t)row * Ndim + col] = v;
        } else {  // MODE 3
          int bb = row >> 11, s = row & 2047;
          if (n0 < 2048) {
            int hh = col >> 7, d = col & 127;
            outQ[((((size_t)bb << 4) + hh) * 2048 + s) * 128 + d] = f2b(v + bq_[col]);
          } else if (n0 < 2560) {
            int c2 = col - 2048, kk = c2 >> 7, d = c2 & 127;
            outK[((((size_t)bb << 2) + kk) * 2048 + s) * 128 + d] = f2b(v + bk_[c2]);
          } else {
            int c2 = col - 2560, kk = c2 >> 7, d = c2 & 127;
            outV[((((size_t)bb << 2) + kk) * 128 + d) * 2048 + s] = f2b(v + bv_[c2]);
          }
        }
      }
    }
  }
}

// ---------------- flash attention v2: swapped QK^T, 32x32x16 MFMA ----------------
// Qb [B][16][S][128] (pre-scaled by 1/sqrt(D), RoPE'd) bf16
// Kb [B][4][S][128] (RoPE'd) bf16, Vt [B][4][128][S] bf16
// AO [B*S][2048] bf16.  256 threads = 4 waves x 32 q-rows, KVBLK=64.
// Per lane: q = lane&31 (lanes l, l+32 hold complementary kv/d halves).
__global__ __launch_bounds__(256, 2) void attn2_k(
    const unsigned short* __restrict__ Qb, const unsigned short* __restrict__ Kb,
    const unsigned short* __restrict__ Vt, unsigned short* __restrict__ AO) {
  __shared__ alignas(16) unsigned short Ks[2][64 * 128];   // [kv][d], slot^=(row&15)
  __shared__ alignas(16) unsigned short Vs[2][128 * 64];   // [d][kv], slot^=(row&7)

  const int tid = threadIdx.x, lane = tid & 63, wid = tid >> 6;
  // XCD-bijective swizzle: 512 blocks, 8 XCDs -> each XCD owns one (b,kvh) K/V pair
  const int hw = blockIdx.x;
  const int work = ((hw & 7) << 6) | (hw >> 3);
  const int qblk = work & 15, bh = work >> 4;
  const int b = bh >> 4, h = bh & 15, kvh = h >> 2;
  const int q0 = qblk << 7;
  const int cl = lane & 31, hi = lane >> 5;

  const unsigned short* Qp = Qb + ((size_t)(b * 16 + h) << 11) * 128;
  const unsigned short* Kp = Kb + ((size_t)(b * 4 + kvh) << 11) * 128;
  const unsigned short* Vp = Vt + ((size_t)(b * 4 + kvh) << 7) * 2048;

  // Q fragments held in registers: B-operand, lane holds Q[qrow][c*16 + hi*8 + 0..7]
  const int qrow = q0 + (wid << 5) + cl;
  bf16x8 qf[8];
#pragma unroll
  for (int c = 0; c < 8; ++c)
    qf[c] = *(const bf16x8*)(Qp + (size_t)qrow * 128 + (c << 4) + (hi << 3));

  f32x16 o[4];
#pragma unroll
  for (int dt = 0; dt < 4; ++dt)
#pragma unroll
    for (int r = 0; r < 16; ++r) o[dt][r] = 0.f;
  float m = -3e38f, l = 0.f;

  auto stage = [&](int t, int buf) {
    const int kv0 = t << 6;
#pragma unroll
    for (int i = 0; i < 4; ++i) {   // K: wave stages 16 rows x 256B
      int row = (wid << 4) + (i << 2) + (lane >> 4);
      int sl = (lane & 15) ^ (row & 15);
      gl2lds16(Kp + ((size_t)(kv0 + row) << 7) + (sl << 3),
               &Ks[buf][(wid << 11) + (i << 9) + (lane << 3)]);
    }
#pragma unroll
    for (int i = 0; i < 4; ++i) {   // V^T: wave stages 32 rows x 128B
      int row = (wid << 5) + (i << 3) + (lane >> 3);
      int sl = (lane & 7) ^ (row & 7);
      gl2lds16(Vp + ((size_t)row << 11) + kv0 + (sl << 3),
               &Vs[buf][(wid << 11) + (i << 9) + (lane << 3)]);
    }
  };

  auto pack8 = [&](float a0, float a1, float a2, float a3,
                   float a4, float a5, float a6, float a7) -> u32x4 {
    u32 x0 = cvtpk_bf16(a0, a1);
    u32 y0 = cvtpk_bf16(a4, a5);
    u32 x1 = cvtpk_bf16(a2, a3);
    u32 y1 = cvtpk_bf16(a6, a7);
    pl32swap(x0, y0);   // x0 -> words (m0,m1); y0 -> (m4,m5)
    pl32swap(x1, y1);   // x1 -> (m2,m3); y1 -> (m6,m7)
    return (u32x4){x0, x1, y0, y1};
  };

  stage(0, 0);
  __syncthreads();

  for (int t = 0; t < 32; ++t) {
    const int buf = t & 1;
    if (t + 1 < 32) stage(t + 1, buf ^ 1);

    // S^T = K Q^T : D[kv][q], kv = (r&3)+8*(r>>2)+4*hi (+32 for s1), q = cl
    f32x16 s0, s1;
#pragma unroll
    for (int r = 0; r < 16; ++r) { s0[r] = 0.f; s1[r] = 0.f; }
#pragma unroll
    for (int c = 0; c < 8; ++c) {
      int sl0 = ((c << 1) + hi) ^ (cl & 15);
      bf16x8 kf0 = *(const bf16x8*)&Ks[buf][(cl << 7) + (sl0 << 3)];
      s0 = __builtin_amdgcn_mfma_f32_32x32x16_bf16(kf0, qf[c], s0, 0, 0, 0);
    }
#pragma unroll
    for (int c = 0; c < 8; ++c) {
      int row = 32 + cl;
      int sl1 = ((c << 1) + hi) ^ (row & 15);
      bf16x8 kf1 = *(const bf16x8*)&Ks[buf][(row << 7) + (sl1 << 3)];
      s1 = __builtin_amdgcn_mfma_f32_32x32x16_bf16(kf1, qf[c], s1, 0, 0, 0);
    }

    // online softmax, in-register (lane owns q = cl; partner lane^32 has other kvs)
    float mx = s0[0];
#pragma unroll
    for (int r = 1; r < 16; ++r) mx = fmaxf(mx, s0[r]);
#pragma unroll
    for (int r = 0; r < 16; ++r) mx = fmaxf(mx, s1[r]);
    mx = fmaxf(mx, __shfl_xor(mx, 32));

    if (!__all(mx <= m + 8.0f)) {       // defer-max: rescale only on real growth
      float mn = fmaxf(m, mx);
      float al = __expf(m - mn);
      m = mn;
      l *= al;
#pragma unroll
      for (int dt = 0; dt < 4; ++dt)
#pragma unroll
        for (int r = 0; r < 16; ++r) o[dt][r] *= al;
    }

    float sum = 0.f;
#pragma unroll
    for (int r = 0; r < 16; ++r) { s0[r] = __expf(s0[r] - m); sum += s0[r]; }
#pragma unroll
    for (int r = 0; r < 16; ++r) { s1[r] = __expf(s1[r] - m); sum += s1[r]; }
    l += sum;

    // P -> bf16 A-fragments via cvt_pk + permlane32_swap (no LDS round trip)
    u32x4 w0 = pack8(s0[0], s0[1], s0[2], s0[3], s0[4], s0[5], s0[6], s0[7]);
    u32x4 w1 = pack8(s0[8], s0[9], s0[10], s0[11], s0[12], s0[13], s0[14], s0[15]);
    u32x4 w2 = pack8(s1[0], s1[1], s1[2], s1[3], s1[4], s1[5], s1[6], s1[7]);
    u32x4 w3 = pack8(s1[8], s1[9], s1[10], s1[11], s1[12], s1[13], s1[14], s1[15]);
    bf16x8 pa0 = __builtin_bit_cast(bf16x8, w0);
    bf16x8 pa1 = __builtin_bit_cast(bf16x8, w1);
    bf16x8 pa2 = __builtin_bit_cast(bf16x8, w2);
    bf16x8 pa3 = __builtin_bit_cast(bf16x8, w3);

    // O^T += V^T P^T : D[d][q]
#pragma unroll
    for (int dt = 0; dt < 4; ++dt) {
      int row = (dt << 5) + cl;
      int sb = row << 6;
      int rx = row & 7;
      bf16x8 vf0 = *(const bf16x8*)&Vs[buf][sb + (((hi) ^ rx) << 3)];
      o[dt] = __builtin_amdgcn_mfma_f32_32x32x16_bf16(vf0, pa0, o[dt], 0, 0, 0);
      bf16x8 vf1 = *(const bf16x8*)&Vs[buf][sb + (((2 + hi) ^ rx) << 3)];
      o[dt] = __builtin_amdgcn_mfma_f32_32x32x16_bf16(vf1, pa1, o[dt], 0, 0, 0);
      bf16x8 vf2 = *(const bf16x8*)&Vs[buf][sb + (((4 + hi) ^ rx) << 3)];
      o[dt] = __builtin_amdgcn_mfma_f32_32x32x16_bf16(vf2, pa2, o[dt], 0, 0, 0);
      bf16x8 vf3 = *(const bf16x8*)&Vs[buf][sb + (((6 + hi) ^ rx) << 3)];
      o[dt] = __builtin_amdgcn_mfma_f32_32x32x16_bf16(vf3, pa3, o[dt], 0, 0, 0);
    }
    __syncthreads();
  }

  float inv = 1.0f / (l + __shfl_xor(l, 32));
  unsigned short* dst = AO + ((size_t)(b * 2048 + qrow) * 2048) + (h << 7);
#pragma unroll
  for (int dt = 0; dt < 4; ++dt) {
#pragma unroll
    for (int rq = 0; rq < 4; ++rq) {
      int d0 = (dt << 5) + (rq << 3) + (hi << 2);
      u16x4 pk = { f2b(o[dt][(rq << 2) + 0] * inv), f2b(o[dt][(rq << 2) + 1] * inv),
                   f2b(o[dt][(rq << 2) + 2] * inv), f2b(o[dt][(rq << 2) + 3] * inv) };
      *(u16x4*)(dst + d0) = pk;
    }
  }
}

// ---------------- launch ----------------
extern "C" void kernel_launch(void* const* d_in, const int* in_sizes, int n_in,
                              void* d_out, int out_size, void* d_ws, size_t ws_size,
                              hipStream_t stream) {
  const float* X  = (const float*)d_in[0];
  const float* Wq = (const float*)d_in[1];
  const float* bq = (const float*)d_in[2];
  const float* Wk = (const float*)d_in[3];
  const float* bk = (const float*)d_in[4];
  const float* Wv = (const float*)d_in[5];
  const float* bv = (const float*)d_in[6];
  const float* Wo = (const float*)d_in[7];
  float* out = (float*)d_out;

  char* ws = (char*)d_ws;
  size_t off = 0;
  auto alloc = [&](size_t bytes) {
    char* p = ws + off;
    off += (bytes + 255) & ~(size_t)255;
    return p;
  };
  unsigned short* Xb    = (unsigned short*)alloc(4096ull * 2048 * 2);
  unsigned short* Wtall = (unsigned short*)alloc(3072ull * 2048 * 2);  // [Wq|Wk|Wv]^T
  unsigned short* Wot   = (unsigned short*)alloc(2048ull * 2048 * 2);
  unsigned short* Qb    = (unsigned short*)alloc(2ull * 16 * 2048 * 128 * 2);
  unsigned short* Kb    = (unsigned short*)alloc(2ull * 4 * 2048 * 128 * 2);
  unsigned short* Vt    = (unsigned short*)alloc(2ull * 4 * 128 * 2048 * 2);
  unsigned short* AO    = (unsigned short*)alloc(4096ull * 2048 * 2);
  float* ctab = (float*)alloc(2048ull * 64 * 4);
  float* stab = (float*)alloc(2048ull * 64 * 4);

  rope_tables_k<<<dim3(2048), dim3(64), 0, stream>>>(ctab, stab);
  cvt4_k<<<dim3(8192), dim3(256), 0, stream>>>(X, Xb, 2097152);
  tcvt_k<<<dim3(64, 64), dim3(32, 8), 0, stream>>>(Wq, Wtall, 2048, 2048);
  tcvt_k<<<dim3(16, 64), dim3(32, 8), 0, stream>>>(Wk, Wtall + 2048ull * 2048, 2048, 512);
  tcvt_k<<<dim3(16, 64), dim3(32, 8), 0, stream>>>(Wv, Wtall + 2560ull * 2048, 2048, 512);
  tcvt_k<<<dim3(64, 64), dim3(32, 8), 0, stream>>>(Wo, Wot, 2048, 2048);

  // fused QKV projection: M=4096, N=3072, K=2048
  gemm_bt_k<3><<<dim3(24, 32), dim3(256), 0, stream>>>(
      Xb, Wtall, nullptr, Qb, Kb, Vt, bq, bk, bv, 4096, 3072, 2048);

  rope_k<true><<<dim3(16384), dim3(256), 0, stream>>>(Qb, ctab, stab, 4194304);
  rope_k<false><<<dim3(4096), dim3(256), 0, stream>>>(Kb, ctab, stab, 1048576);

  attn2_k<<<dim3(512), dim3(256), 0, stream>>>(Qb, Kb, Vt, AO);

  // O projection: M=4096, N=2048, K=2048, fp32 out
  gemm_bt_k<0><<<dim3(16, 32), dim3(256), 0, stream>>>(
      AO, Wot, out, nullptr, nullptr, nullptr, nullptr, nullptr, nullptr, 4096, 2048, 2048);
}